// Round 4
// baseline (1721.756 us; speedup 1.0000x reference)
//
#include <hip/hip_runtime.h>
#include <math.h>

// ---------------------------------------------------------------------------
// Round 4: persistent LSTM chain. One kernel (768 blocks, all co-resident,
// 3/CU) runs all 14 timesteps with a device-wide counter barrier between
// steps. c-state lives in 16 VGPRs per lane (block-stationary mapping),
// eliminating the 23 MB/step fp32 c round-trip and 13 launch gaps.
// Gate-interleaved weights: n' = (u>>4)*64 + g*16 + (u&15). MLP unchanged.
// ---------------------------------------------------------------------------

using bf16x8 = __attribute__((ext_vector_type(8))) short;
using f32x4  = __attribute__((ext_vector_type(4))) float;

enum { EPI_NONE = 0, EPI_RELU = 1, EPI_TANH = 2 };

__device__ inline unsigned short f2bf(float f) {
    union { float f; unsigned u; } v; v.f = f;
    unsigned r = v.u + 0x7FFFu + ((v.u >> 16) & 1u);
    return (unsigned short)(r >> 16);
}
__device__ inline float sigf(float x) { return 1.f / (1.f + expf(-x)); }

__device__ inline void gll16(const void* g, void* l) {
    __builtin_amdgcn_global_load_lds(
        (const __attribute__((address_space(1))) unsigned int*)(uintptr_t)g,
        (__attribute__((address_space(3))) unsigned int*)(unsigned int)(uintptr_t)l,
        16, 0, 0);
}

// ---- shared GEMM core: stage 128x32 A/B tiles, 4 waves 2x2, 16x16x32 ----
#define GEMM_CORE(A_, Bt_, K_)                                                 \
    for (int k0 = 0; k0 < (K_); k0 += 32) {                                    \
        _Pragma("unroll")                                                      \
        for (int j = 0; j < 2; ++j) {                                          \
            const int idx = j * 256 + tid;                                     \
            const int row = idx >> 2, kc = idx & 3;                            \
            gll16((A_)  + (size_t)(m0 + row) * (K_) + k0 + kc * 8, As + idx*8);\
            gll16((Bt_) + (size_t)(n0 + row) * (K_) + k0 + kc * 8, Bs + idx*8);\
        }                                                                      \
        __syncthreads();                                                       \
        bf16x8 aF[4], bF[4];                                                   \
        _Pragma("unroll")                                                      \
        for (int mi = 0; mi < 4; ++mi)                                         \
            aF[mi] = *(const bf16x8*)(As + (wr*64 + mi*16 + lm)*32 + quad*8);  \
        _Pragma("unroll")                                                      \
        for (int ni = 0; ni < 4; ++ni)                                         \
            bF[ni] = *(const bf16x8*)(Bs + (wc*64 + ni*16 + lm)*32 + quad*8);  \
        _Pragma("unroll")                                                      \
        for (int mi = 0; mi < 4; ++mi)                                         \
            _Pragma("unroll")                                                  \
            for (int ni = 0; ni < 4; ++ni)                                     \
                acc[mi][ni] = __builtin_amdgcn_mfma_f32_16x16x32_bf16(         \
                    aF[mi], bF[ni], acc[mi][ni], 0, 0, 0);                     \
        __syncthreads();                                                       \
    }

// ---- plain GEMM (MLP): C = act(A @ Bt^T + bias) ----
template <int EPI, int OUT_BF16, int NGUARD>
__global__ __launch_bounds__(256)
void gemm_mfma(const unsigned short* __restrict__ A,
               const unsigned short* __restrict__ Bt,
               const float* __restrict__ bias,
               void* __restrict__ Cv, int ldc, int Nreal, int K)
{
    __shared__ __attribute__((aligned(16))) unsigned short As[128 * 32];
    __shared__ __attribute__((aligned(16))) unsigned short Bs[128 * 32];
    const int tid  = threadIdx.x;
    const int lane = tid & 63;
    const int w    = tid >> 6;
    const int wr   = w >> 1, wc = w & 1;
    const int lm   = lane & 15, quad = lane >> 4;
    const int m0   = blockIdx.x * 128, n0 = blockIdx.y * 128;
    f32x4 acc[4][4] = {};
    GEMM_CORE(A, Bt, K)
    #pragma unroll
    for (int mi = 0; mi < 4; ++mi)
        #pragma unroll
        for (int r = 0; r < 4; ++r) {
            const size_t row = m0 + wr * 64 + mi * 16 + quad * 4 + r;
            #pragma unroll
            for (int ni = 0; ni < 4; ++ni) {
                const int col = n0 + wc * 64 + ni * 16 + lm;
                if (!NGUARD || col < Nreal) {
                    float v = acc[mi][ni][r] + bias[col];
                    if (EPI == EPI_RELU) v = fmaxf(v, 0.f);
                    if (EPI == EPI_TANH) v = tanhf(v);
                    if (OUT_BF16) ((unsigned short*)Cv)[row * ldc + col] = f2bf(v);
                    else          ((float*)Cv)[row * ldc + col] = v;
                }
            }
        }
}

// ---- persistent LSTM chain: all 14 steps, c in registers ----
// grid MUST be dim3(64,12) = 768 blocks; __launch_bounds__(256,3) guarantees
// >=3 blocks/CU so all 768 are co-resident (LDS 16KB -> 10/CU; VGPR capped).
__global__ __launch_bounds__(256, 3)
void lstm_chain(const unsigned short* __restrict__ AcE,
                const unsigned short* __restrict__ AcD,
                const unsigned short* __restrict__ WtE,
                const unsigned short* __restrict__ WtD,
                const float* __restrict__ bIE,
                const float* __restrict__ bID,
                unsigned short* __restrict__ dcd,
                unsigned int* __restrict__ ctr)
{
    __shared__ __attribute__((aligned(16))) unsigned short As[128 * 32];
    __shared__ __attribute__((aligned(16))) unsigned short Bs[128 * 32];
    const int tid  = threadIdx.x;
    const int lane = tid & 63;
    const int w    = tid >> 6;
    const int wr   = w >> 1, wc = w & 1;
    const int lm   = lane & 15, quad = lane >> 4;
    const int m0   = blockIdx.x * 128, n0 = blockIdx.y * 128;

    const int u = ((n0 + wc * 64) >> 6) * 16 + lm;
    const bool uvalid = (u < 356);

    float creg[4][4] = {};   // c0 = 0; block-stationary across all steps

    for (int step = 0; step < 14; ++step) {
        const bool enc = (step < 7);
        const int td = step - 7;
        const unsigned short* A  = enc ? AcE + (size_t)step * 8192 * 448
                                       : AcD + (size_t)td   * 8192 * 416;
        const unsigned short* Bt = enc ? WtE : WtD;
        const float* bI          = enc ? bIE : bID;
        const int K              = enc ? 448 : 416;

        f32x4 acc[4][4] = {};
        GEMM_CORE(A, Bt, K)

        if (uvalid) {
            float b0 = bI[n0 + wc * 64 + lm];
            float b1 = bI[n0 + wc * 64 + 16 + lm];
            float b2 = bI[n0 + wc * 64 + 32 + lm];
            float b3 = bI[n0 + wc * 64 + 48 + lm];
            unsigned short* hdst;
            int ldh, hoff;
            if (enc) {
                if (step < 6) { hdst = (unsigned short*)AcE + (size_t)(step + 1) * 8192 * 448; ldh = 448; hoff = 69; }
                else          { hdst = (unsigned short*)AcD; ldh = 416; hoff = 45; }
            } else {
                hdst = (td < 6) ? (unsigned short*)AcD + (size_t)(td + 1) * 8192 * 416 : nullptr;
                ldh = 416; hoff = 45;
            }
            #pragma unroll
            for (int mi = 0; mi < 4; ++mi)
                #pragma unroll
                for (int r = 0; r < 4; ++r) {
                    const size_t row = m0 + wr * 64 + mi * 16 + quad * 4 + r;
                    const float zi = acc[mi][0][r] + b0;
                    const float zf = acc[mi][1][r] + b1;
                    const float zg = acc[mi][2][r] + b2;
                    const float zo = acc[mi][3][r] + b3;
                    const float cn = sigf(zf) * creg[mi][r] + sigf(zi) * tanhf(zg);
                    creg[mi][r] = cn;
                    const unsigned short hb = f2bf(sigf(zo) * tanhf(cn));
                    if (hdst) hdst[row * (size_t)ldh + hoff + u] = hb;
                    if (!enc) dcd[row * (size_t)2496 + td * 356 + u] = hb;
                }
        }

        if (step < 13) {
            __syncthreads();               // all block stores drained (vmcnt)
            if (tid == 0) {
                __threadfence();           // release: L2 writeback, device scope
                atomicAdd(ctr, 1u);
                const unsigned int target = 768u * (unsigned)(step + 1);
                while (__hip_atomic_load(ctr, __ATOMIC_RELAXED,
                                         __HIP_MEMORY_SCOPE_AGENT) < target)
                    __builtin_amdgcn_s_sleep(2);
                __threadfence();           // acquire: invalidate stale lines
            }
            __syncthreads();
        }
    }
}

// ---- LSTM weight pack: [Wa;Wb] fp32 [K][1424] -> Wt bf16 [1536][Kp],
// col-interleaved, zero-padded; also biasI. ----
__global__ void pack_lstm(const float* __restrict__ Wa,
                          const float* __restrict__ Wb, int K1, int K,
                          const float* __restrict__ bias,
                          unsigned short* __restrict__ Wt,
                          float* __restrict__ biasI, int Kp)
{
    const int idx = blockIdx.x * 256 + threadIdx.x;
    if (idx >= 1536 * Kp) return;
    const int np = idx / Kp, k = idx - np * Kp;
    const int ub = np >> 6, g = (np >> 4) & 3, ul = np & 15;
    const int u = ub * 16 + ul;
    const bool valid = (u < 356);
    const int norig = g * 356 + u;
    float v = 0.f;
    if (valid && k < K)
        v = (k < K1) ? Wa[(size_t)k * 1424 + norig]
                     : Wb[(size_t)(k - K1) * 1424 + norig];
    Wt[(size_t)np * Kp + k] = f2bf(v);
    if (k == 0) biasI[np] = valid ? bias[norig] : 0.f;
}

// ---- MLP weight transpose+pack (fp32 [K][N] -> bf16 [Np][Kp], zero-pad) ----
__global__ void transpose_pack(const float* __restrict__ W, int K, int N,
                               unsigned short* __restrict__ Wt, int Kp, int Np)
{
    __shared__ float t[32][33];
    const int n0 = blockIdx.x * 32, k0 = blockIdx.y * 32;
    const int tx = threadIdx.x, ty = threadIdx.y;
    #pragma unroll
    for (int r = 0; r < 4; ++r) {
        const int k = k0 + ty + 8 * r, n = n0 + tx;
        t[ty + 8 * r][tx] = (k < K && n < N) ? W[(size_t)k * N + n] : 0.f;
    }
    __syncthreads();
    #pragma unroll
    for (int r = 0; r < 4; ++r) {
        const int k = k0 + tx, n = n0 + ty + 8 * r;
        if (k < Kp && n < Np) Wt[(size_t)n * Kp + k] = f2bf(t[tx][ty + 8 * r]);
    }
}

// ---- fill x/m time-slices into the 7 per-step concat buffers (bf16) ----
__global__ void fill_slices(const float* __restrict__ src,
                            unsigned short* __restrict__ bufs,
                            int F, int Kp, int n)  // n = B*7*F
{
    const int i = blockIdx.x * 256 + threadIdx.x;
    if (i >= n) return;
    const int b = i / (7 * F), rem = i - b * 7 * F;
    const int t = rem / F, f = rem - t * F;
    bufs[(size_t)t * 8192 * Kp + (size_t)b * Kp + f] = f2bf(src[i]);
}

extern "C" void kernel_launch(void* const* d_in, const int* in_sizes, int n_in,
                              void* d_out, int out_size, void* d_ws, size_t ws_size,
                              hipStream_t stream)
{
    const float* x     = (const float*)d_in[0];
    const float* m     = (const float*)d_in[1];
    const float* enc_W = (const float*)d_in[2];
    const float* enc_U = (const float*)d_in[3];
    const float* enc_b = (const float*)d_in[4];
    const float* dec_W = (const float*)d_in[5];
    const float* dec_Um= (const float*)d_in[6];
    const float* dec_b = (const float*)d_in[7];
    const float* W_map = (const float*)d_in[8];
    const float* b_map = (const float*)d_in[9];
    const float* W1    = (const float*)d_in[10];
    const float* b1    = (const float*)d_in[11];
    const float* W2    = (const float*)d_in[12];
    const float* b2    = (const float*)d_in[13];
    const float* W3    = (const float*)d_in[14];
    const float* b3    = (const float*)d_in[15];
    const float* W_out = (const float*)d_in[16];
    const float* b_out = (const float*)d_in[17];
    float* out = (float*)d_out;

    const int B = 8192, T = 7, FE = 69, FD = 45;
    const int KE = 448, KD = 416;     // pad32(69+356), pad32(45+356)
    const int KMP = 2496;             // pad32(7*356)

    char* ws = (char*)d_ws;
    size_t off = 0;
    auto alloc = [&](size_t bytes) -> void* {
        void* p = ws + off; off = (off + bytes + 255) & ~(size_t)255; return p;
    };
    unsigned short* WtE = (unsigned short*)alloc((size_t)1536 * KE * 2);
    unsigned short* WtD = (unsigned short*)alloc((size_t)1536 * KD * 2);
    unsigned short* WtM = (unsigned short*)alloc((size_t)1024 * KMP * 2);
    unsigned short* Wt1 = (unsigned short*)alloc((size_t)1024 * 1024 * 2);
    unsigned short* Wt2 = (unsigned short*)alloc((size_t)1024 * 1024 * 2);
    unsigned short* Wt3 = (unsigned short*)alloc((size_t)1024 * 1024 * 2);
    unsigned short* WtO = (unsigned short*)alloc((size_t)256 * 1024 * 2);
    float* bIE = (float*)alloc(1536 * 4);
    float* bID = (float*)alloc(1536 * 4);
    unsigned short* AcE = (unsigned short*)alloc((size_t)T * B * KE * 2);
    unsigned short* AcD = (unsigned short*)alloc((size_t)T * B * KD * 2);
    unsigned short* dcd = (unsigned short*)alloc((size_t)B * KMP * 2);
    unsigned short* a1  = (unsigned short*)alloc((size_t)B * 1024 * 2);
    unsigned short* a2  = (unsigned short*)alloc((size_t)B * 1024 * 2);
    unsigned int* ctr = (unsigned int*)alloc(256);

    // ---- weight packing (off critical path) ----
    pack_lstm<<<(1536 * KE + 255) / 256, 256, 0, stream>>>(
        enc_W, enc_U, FE, FE + 356, enc_b, WtE, bIE, KE);
    pack_lstm<<<(1536 * KD + 255) / 256, 256, 0, stream>>>(
        dec_W, dec_Um, FD, FD + 356, dec_b, WtD, bID, KD);
    const dim3 tb(32, 8);
    transpose_pack<<<dim3(1024 / 32, KMP / 32), tb, 0, stream>>>(
        W_map, 2492, 1024, WtM, KMP, 1024);
    transpose_pack<<<dim3(32, 32), tb, 0, stream>>>(W1, 1024, 1024, Wt1, 1024, 1024);
    transpose_pack<<<dim3(32, 32), tb, 0, stream>>>(W2, 1024, 1024, Wt2, 1024, 1024);
    transpose_pack<<<dim3(32, 32), tb, 0, stream>>>(W3, 1024, 1024, Wt3, 1024, 1024);
    transpose_pack<<<dim3(256 / 32, 1024 / 32), tb, 0, stream>>>(
        W_out, 1024, 168, WtO, 1024, 256);

    // ---- zero A buffers (pads + t=0 h region; ws is 0xAA-poisoned) ----
    hipMemsetAsync(AcE, 0, (size_t)T * B * KE * 2, stream);
    hipMemsetAsync(AcD, 0, (size_t)T * B * KD * 2, stream);
    hipMemsetAsync(dcd, 0, (size_t)B * KMP * 2, stream);
    hipMemsetAsync(ctr, 0, 4, stream);

    fill_slices<<<(B * T * FE + 255) / 256, 256, 0, stream>>>(x, AcE, FE, KE, B * T * FE);
    fill_slices<<<(B * T * FD + 255) / 256, 256, 0, stream>>>(m, AcD, FD, KD, B * T * FD);

    // ---- persistent LSTM chain: one launch, 14 steps ----
    lstm_chain<<<dim3(64, 12), 256, 0, stream>>>(
        AcE, AcD, WtE, WtD, bIE, bID, dcd, ctr);

    // ---- MLP head ----
    gemm_mfma<EPI_RELU, 1, 0><<<dim3(64, 8), 256, 0, stream>>>(
        dcd, WtM, b_map, a1, 1024, 1024, KMP);
    gemm_mfma<EPI_TANH, 1, 0><<<dim3(64, 8), 256, 0, stream>>>(
        a1, Wt1, b1, a2, 1024, 1024, 1024);
    gemm_mfma<EPI_TANH, 1, 0><<<dim3(64, 8), 256, 0, stream>>>(
        a2, Wt2, b2, a1, 1024, 1024, 1024);
    gemm_mfma<EPI_TANH, 1, 0><<<dim3(64, 8), 256, 0, stream>>>(
        a1, Wt3, b3, a2, 1024, 1024, 1024);
    gemm_mfma<EPI_NONE, 0, 1><<<dim3(64, 2), 256, 0, stream>>>(
        a2, WtO, b_out, out, 168, 168, 1024);
}

// Round 5
// 1164.076 us; speedup vs baseline: 1.4791x; 1.4791x over previous
//
#include <hip/hip_runtime.h>
#include <math.h>

// ---------------------------------------------------------------------------
// Round 5: block-local persistent LSTM chain — NO cross-block sync.
// Each block owns 32 batch rows and the FULL gate dimension (1536 cols):
// h (bf16) and c (fp32) stay in LDS for all 14 steps. B-fragments are read
// register-direct from global (L2-cached weights), A-fragments from the
// LDS-resident [x_t | h] buffer; no inner-loop barriers (2 syncs/step).
// Weights gate-interleaved: n' = (u>>4)*64 + g*16 + (u&15), Kp=448 for both.
// MLP head unchanged (round-3 structure).
// ---------------------------------------------------------------------------

using bf16x8 = __attribute__((ext_vector_type(8))) short;
using f32x4  = __attribute__((ext_vector_type(4))) float;

enum { EPI_NONE = 0, EPI_RELU = 1, EPI_TANH = 2 };

__device__ inline unsigned short f2bf(float f) {
    union { float f; unsigned u; } v; v.f = f;
    unsigned r = v.u + 0x7FFFu + ((v.u >> 16) & 1u);
    return (unsigned short)(r >> 16);
}
__device__ inline float sigf(float x) { return 1.f / (1.f + expf(-x)); }

__device__ inline void gll16(const void* g, void* l) {
    __builtin_amdgcn_global_load_lds(
        (const __attribute__((address_space(1))) unsigned int*)(uintptr_t)g,
        (__attribute__((address_space(3))) unsigned int*)(unsigned int)(uintptr_t)l,
        16, 0, 0);
}

// ---- MLP GEMM core (round-3 structure, unchanged) ----
#define GEMM_CORE(A_, Bt_, K_)                                                 \
    for (int k0 = 0; k0 < (K_); k0 += 32) {                                    \
        _Pragma("unroll")                                                      \
        for (int j = 0; j < 2; ++j) {                                          \
            const int idx = j * 256 + tid;                                     \
            const int row = idx >> 2, kc = idx & 3;                            \
            gll16((A_)  + (size_t)(m0 + row) * (K_) + k0 + kc * 8, As + idx*8);\
            gll16((Bt_) + (size_t)(n0 + row) * (K_) + k0 + kc * 8, Bs + idx*8);\
        }                                                                      \
        __syncthreads();                                                       \
        bf16x8 aF[4], bF[4];                                                   \
        _Pragma("unroll")                                                      \
        for (int mi = 0; mi < 4; ++mi)                                         \
            aF[mi] = *(const bf16x8*)(As + (wr*64 + mi*16 + lm)*32 + quad*8);  \
        _Pragma("unroll")                                                      \
        for (int ni = 0; ni < 4; ++ni)                                         \
            bF[ni] = *(const bf16x8*)(Bs + (wc*64 + ni*16 + lm)*32 + quad*8);  \
        _Pragma("unroll")                                                      \
        for (int mi = 0; mi < 4; ++mi)                                         \
            _Pragma("unroll")                                                  \
            for (int ni = 0; ni < 4; ++ni)                                     \
                acc[mi][ni] = __builtin_amdgcn_mfma_f32_16x16x32_bf16(         \
                    aF[mi], bF[ni], acc[mi][ni], 0, 0, 0);                     \
        __syncthreads();                                                       \
    }

template <int EPI, int OUT_BF16, int NGUARD>
__global__ __launch_bounds__(256)
void gemm_mfma(const unsigned short* __restrict__ A,
               const unsigned short* __restrict__ Bt,
               const float* __restrict__ bias,
               void* __restrict__ Cv, int ldc, int Nreal, int K)
{
    __shared__ __attribute__((aligned(16))) unsigned short As[128 * 32];
    __shared__ __attribute__((aligned(16))) unsigned short Bs[128 * 32];
    const int tid  = threadIdx.x;
    const int lane = tid & 63;
    const int w    = tid >> 6;
    const int wr   = w >> 1, wc = w & 1;
    const int lm   = lane & 15, quad = lane >> 4;
    const int m0   = blockIdx.x * 128, n0 = blockIdx.y * 128;
    f32x4 acc[4][4] = {};
    GEMM_CORE(A, Bt, K)
    #pragma unroll
    for (int mi = 0; mi < 4; ++mi)
        #pragma unroll
        for (int r = 0; r < 4; ++r) {
            const size_t row = m0 + wr * 64 + mi * 16 + quad * 4 + r;
            #pragma unroll
            for (int ni = 0; ni < 4; ++ni) {
                const int col = n0 + wc * 64 + ni * 16 + lm;
                if (!NGUARD || col < Nreal) {
                    float v = acc[mi][ni][r] + bias[col];
                    if (EPI == EPI_RELU) v = fmaxf(v, 0.f);
                    if (EPI == EPI_TANH) v = tanhf(v);
                    if (OUT_BF16) ((unsigned short*)Cv)[row * ldc + col] = f2bf(v);
                    else          ((float*)Cv)[row * ldc + col] = v;
                }
            }
        }
}

// ---- block-local LSTM chain ----
// grid = 256 blocks (32 rows each), 256 threads = 4 waves, each wave owns
// 64 of the 256 cols per n-iteration (6 n-iters cover N=1536).
// LDS: Abuf [32][456] bf16 (x|h|pad, stride 456 -> 2-way-free banks),
//      cbuf [32][361] f32, hbuf [32][360] bf16.
__global__ __launch_bounds__(256, 1)
void lstm_chain_local(const float* __restrict__ xg,
                      const float* __restrict__ mg,
                      const unsigned short* __restrict__ WtE,
                      const unsigned short* __restrict__ WtD,
                      const float* __restrict__ bIE,
                      const float* __restrict__ bID,
                      unsigned short* __restrict__ dcd)
{
    __shared__ __attribute__((aligned(16))) unsigned short Abuf[32 * 456];
    __shared__ float cbuf[32 * 361];
    __shared__ unsigned short hbuf[32 * 360];

    const int tid  = threadIdx.x;
    const int lane = tid & 63;
    const int w    = tid >> 6;          // wave id 0..3 -> 64-col group
    const int lm   = lane & 15, quad = lane >> 4;
    const int m0   = blockIdx.x * 32;

    for (int i = tid; i < 32 * 456; i += 256) Abuf[i] = 0;
    for (int i = tid; i < 32 * 361; i += 256) cbuf[i] = 0.f;

    for (int step = 0; step < 14; ++step) {
        const bool enc = step < 7;
        const int  td  = step - 7;
        const int  F   = enc ? 69 : 45;
        const int  tt  = enc ? step : td;
        const float* src = enc ? xg : mg;
        const unsigned short* Wt = enc ? WtE : WtD;
        const float* bI = enc ? bIE : bID;

        // stage x/m time-slice into cols 0..F-1 (disjoint from h cols)
        for (int i = tid; i < 32 * F; i += 256) {
            const int r = i / F, f = i - r * F;
            Abuf[r * 456 + f] = f2bf(src[((size_t)(m0 + r) * 7 + tt) * F + f]);
        }
        if (!enc && td == 0) {   // clear stale enc-h tail cols 401..455
            for (int i = tid; i < 32 * 55; i += 256) {
                const int r = i / 55, cc = 401 + (i - r * 55);
                Abuf[r * 456 + cc] = 0;
            }
        }
        __syncthreads();   // staging + prev h-copy visible to all waves

        // barrier-free GEMM: z[32][1536] = Abuf @ Wt^T, 6 n-iters of 256 cols
        #pragma unroll 1
        for (int nt = 0; nt < 6; ++nt) {
            const int nbase = nt * 256 + w * 64;
            const unsigned short* bp0 = Wt + (size_t)(nbase + lm) * 448 + quad * 8;
            const unsigned short* bp1 = bp0 + 16 * 448;
            const unsigned short* bp2 = bp0 + 32 * 448;
            const unsigned short* bp3 = bp0 + 48 * 448;
            f32x4 acc[2][4] = {};
            bf16x8 bA[4], bB[4];
            bA[0] = *(const bf16x8*)(bp0);      bA[1] = *(const bf16x8*)(bp1);
            bA[2] = *(const bf16x8*)(bp2);      bA[3] = *(const bf16x8*)(bp3);
            bB[0] = *(const bf16x8*)(bp0 + 32); bB[1] = *(const bf16x8*)(bp1 + 32);
            bB[2] = *(const bf16x8*)(bp2 + 32); bB[3] = *(const bf16x8*)(bp3 + 32);
            #pragma unroll
            for (int k0 = 0; k0 < 448; k0 += 32) {
                const int kp = (k0 + 64 < 448) ? (k0 + 64) : 0;  // dummy wrap
                bf16x8 bC[4];
                bC[0] = *(const bf16x8*)(bp0 + kp);
                bC[1] = *(const bf16x8*)(bp1 + kp);
                bC[2] = *(const bf16x8*)(bp2 + kp);
                bC[3] = *(const bf16x8*)(bp3 + kp);
                bf16x8 aF[2];
                aF[0] = *(const bf16x8*)(Abuf + (size_t)lm * 456 + k0 + quad * 8);
                aF[1] = *(const bf16x8*)(Abuf + (size_t)(16 + lm) * 456 + k0 + quad * 8);
                #pragma unroll
                for (int mi = 0; mi < 2; ++mi)
                    #pragma unroll
                    for (int ni = 0; ni < 4; ++ni)
                        acc[mi][ni] = __builtin_amdgcn_mfma_f32_16x16x32_bf16(
                            aF[mi], bA[ni], acc[mi][ni], 0, 0, 0);
                #pragma unroll
                for (int ni = 0; ni < 4; ++ni) { bA[ni] = bB[ni]; bB[ni] = bC[ni]; }
            }
            // epilogue: 4 ni-accs = gates (i,f,g,o) of unit u
            const int u = (nt * 4 + w) * 16 + lm;
            if (u < 356) {
                const float b0 = bI[nbase + lm];
                const float b1 = bI[nbase + 16 + lm];
                const float b2 = bI[nbase + 32 + lm];
                const float b3 = bI[nbase + 48 + lm];
                #pragma unroll
                for (int mi = 0; mi < 2; ++mi)
                    #pragma unroll
                    for (int r = 0; r < 4; ++r) {
                        const int row = mi * 16 + quad * 4 + r;
                        const float zi = acc[mi][0][r] + b0;
                        const float zf = acc[mi][1][r] + b1;
                        const float zg = acc[mi][2][r] + b2;
                        const float zo = acc[mi][3][r] + b3;
                        const float cn = sigf(zf) * cbuf[row * 361 + u]
                                       + sigf(zi) * tanhf(zg);
                        cbuf[row * 361 + u] = cn;
                        hbuf[row * 360 + u] = f2bf(sigf(zo) * tanhf(cn));
                    }
            }
        }
        __syncthreads();   // all A reads + hbuf writes complete

        // h-copy: hbuf -> Abuf h-region (next step) and dcd (decoder)
        const int hoff = (step < 6) ? 69 : 45;
        for (int i = tid; i < 32 * 356; i += 256) {
            const int r = i / 356, u = i - r * 356;
            const unsigned short hv = hbuf[r * 360 + u];
            if (step < 13) Abuf[r * 456 + hoff + u] = hv;
            if (!enc) dcd[(size_t)(m0 + r) * 2496 + td * 356 + u] = hv;
        }
        // next iteration's staging (cols 0..F-1) is disjoint from h cols;
        // the top __syncthreads() orders everything before the next GEMM.
    }
}

// ---- LSTM weight pack: [Wa;Wb] fp32 [K][1424] -> Wt bf16 [1536][448],
// gate-interleaved cols, zero-padded; also interleaved bias. ----
__global__ void pack_lstm(const float* __restrict__ Wa,
                          const float* __restrict__ Wb, int K1, int K,
                          const float* __restrict__ bias,
                          unsigned short* __restrict__ Wt,
                          float* __restrict__ biasI, int Kp)
{
    const int idx = blockIdx.x * 256 + threadIdx.x;
    if (idx >= 1536 * Kp) return;
    const int np = idx / Kp, k = idx - np * Kp;
    const int ub = np >> 6, g = (np >> 4) & 3, ul = np & 15;
    const int u = ub * 16 + ul;
    const bool valid = (u < 356);
    const int norig = g * 356 + u;
    float v = 0.f;
    if (valid && k < K)
        v = (k < K1) ? Wa[(size_t)k * 1424 + norig]
                     : Wb[(size_t)(k - K1) * 1424 + norig];
    Wt[(size_t)np * Kp + k] = f2bf(v);
    if (k == 0) biasI[np] = valid ? bias[norig] : 0.f;
}

// ---- MLP weight transpose+pack (fp32 [K][N] -> bf16 [Np][Kp], zero-pad) ----
__global__ void transpose_pack(const float* __restrict__ W, int K, int N,
                               unsigned short* __restrict__ Wt, int Kp, int Np)
{
    __shared__ float t[32][33];
    const int n0 = blockIdx.x * 32, k0 = blockIdx.y * 32;
    const int tx = threadIdx.x, ty = threadIdx.y;
    #pragma unroll
    for (int r = 0; r < 4; ++r) {
        const int k = k0 + ty + 8 * r, n = n0 + tx;
        t[ty + 8 * r][tx] = (k < K && n < N) ? W[(size_t)k * N + n] : 0.f;
    }
    __syncthreads();
    #pragma unroll
    for (int r = 0; r < 4; ++r) {
        const int k = k0 + tx, n = n0 + ty + 8 * r;
        if (k < Kp && n < Np) Wt[(size_t)n * Kp + k] = f2bf(t[tx][ty + 8 * r]);
    }
}

extern "C" void kernel_launch(void* const* d_in, const int* in_sizes, int n_in,
                              void* d_out, int out_size, void* d_ws, size_t ws_size,
                              hipStream_t stream)
{
    const float* x     = (const float*)d_in[0];
    const float* m     = (const float*)d_in[1];
    const float* enc_W = (const float*)d_in[2];
    const float* enc_U = (const float*)d_in[3];
    const float* enc_b = (const float*)d_in[4];
    const float* dec_W = (const float*)d_in[5];
    const float* dec_Um= (const float*)d_in[6];
    const float* dec_b = (const float*)d_in[7];
    const float* W_map = (const float*)d_in[8];
    const float* b_map = (const float*)d_in[9];
    const float* W1    = (const float*)d_in[10];
    const float* b1    = (const float*)d_in[11];
    const float* W2    = (const float*)d_in[12];
    const float* b2    = (const float*)d_in[13];
    const float* W3    = (const float*)d_in[14];
    const float* b3    = (const float*)d_in[15];
    const float* W_out = (const float*)d_in[16];
    const float* b_out = (const float*)d_in[17];
    float* out = (float*)d_out;

    const int B = 8192;
    const int KMP = 2496;   // pad32(7*356)

    char* ws = (char*)d_ws;
    size_t off = 0;
    auto alloc = [&](size_t bytes) -> void* {
        void* p = ws + off; off = (off + bytes + 255) & ~(size_t)255; return p;
    };
    unsigned short* WtE = (unsigned short*)alloc((size_t)1536 * 448 * 2);
    unsigned short* WtD = (unsigned short*)alloc((size_t)1536 * 448 * 2);
    unsigned short* WtM = (unsigned short*)alloc((size_t)1024 * KMP * 2);
    unsigned short* Wt1 = (unsigned short*)alloc((size_t)1024 * 1024 * 2);
    unsigned short* Wt2 = (unsigned short*)alloc((size_t)1024 * 1024 * 2);
    unsigned short* Wt3 = (unsigned short*)alloc((size_t)1024 * 1024 * 2);
    unsigned short* WtO = (unsigned short*)alloc((size_t)256 * 1024 * 2);
    float* bIE = (float*)alloc(1536 * 4);
    float* bID = (float*)alloc(1536 * 4);
    unsigned short* dcd = (unsigned short*)alloc((size_t)B * KMP * 2);
    unsigned short* a1  = (unsigned short*)alloc((size_t)B * 1024 * 2);
    unsigned short* a2  = (unsigned short*)alloc((size_t)B * 1024 * 2);

    // ---- weight packing (parallel, before chain) ----
    pack_lstm<<<(1536 * 448 + 255) / 256, 256, 0, stream>>>(
        enc_W, enc_U, 69, 425, enc_b, WtE, bIE, 448);
    pack_lstm<<<(1536 * 448 + 255) / 256, 256, 0, stream>>>(
        dec_W, dec_Um, 45, 401, dec_b, WtD, bID, 448);
    const dim3 tb(32, 8);
    transpose_pack<<<dim3(1024 / 32, KMP / 32), tb, 0, stream>>>(
        W_map, 2492, 1024, WtM, KMP, 1024);
    transpose_pack<<<dim3(32, 32), tb, 0, stream>>>(W1, 1024, 1024, Wt1, 1024, 1024);
    transpose_pack<<<dim3(32, 32), tb, 0, stream>>>(W2, 1024, 1024, Wt2, 1024, 1024);
    transpose_pack<<<dim3(32, 32), tb, 0, stream>>>(W3, 1024, 1024, Wt3, 1024, 1024);
    transpose_pack<<<dim3(256 / 32, 1024 / 32), tb, 0, stream>>>(
        W_out, 1024, 168, WtO, 1024, 256);

    // dcd pad cols (2492..2495) must be zero for the W_map GEMM
    hipMemsetAsync(dcd, 0, (size_t)B * KMP * 2, stream);

    // ---- one launch: all 14 LSTM steps, block-local ----
    lstm_chain_local<<<256, 256, 0, stream>>>(x, m, WtE, WtD, bIE, bID, dcd);

    // ---- MLP head ----
    gemm_mfma<EPI_RELU, 1, 0><<<dim3(64, 8), 256, 0, stream>>>(
        dcd, WtM, b_map, a1, 1024, 1024, KMP);
    gemm_mfma<EPI_TANH, 1, 0><<<dim3(64, 8), 256, 0, stream>>>(
        a1, Wt1, b1, a2, 1024, 1024, 1024);
    gemm_mfma<EPI_TANH, 1, 0><<<dim3(64, 8), 256, 0, stream>>>(
        a2, Wt2, b2, a1, 1024, 1024, 1024);
    gemm_mfma<EPI_TANH, 1, 0><<<dim3(64, 8), 256, 0, stream>>>(
        a1, Wt3, b3, a2, 1024, 1024, 1024);
    gemm_mfma<EPI_NONE, 0, 1><<<dim3(64, 2), 256, 0, stream>>>(
        a2, WtO, b_out, out, 168, 168, 1024);
}

// Round 6
// 714.371 us; speedup vs baseline: 2.4102x; 1.6295x over previous
//
#include <hip/hip_runtime.h>
#include <math.h>

// ---------------------------------------------------------------------------
// Round 6: round-3 structure (best: 759 us) + fast transcendentals
// (__expf/__fdividef epilogues instead of libm tanhf), targeted pad-zeroing
// instead of 140 MB of memsets, fused W1/W2/W3 transpose.
// Persistent-chain variants (r4: device barrier = 78 us/step; r5: 4 waves/CU
// latency-bound) both lost to 14 plain launches — keep launches.
// ---------------------------------------------------------------------------

using bf16x8 = __attribute__((ext_vector_type(8))) short;
using f32x4  = __attribute__((ext_vector_type(4))) float;

enum { EPI_NONE = 0, EPI_RELU = 1, EPI_TANH = 2 };

__device__ inline unsigned short f2bf(float f) {
    union { float f; unsigned u; } v; v.f = f;
    unsigned r = v.u + 0x7FFFu + ((v.u >> 16) & 1u);
    return (unsigned short)(r >> 16);
}
// fast sigmoid/tanh: v_exp_f32-based, ~5 instr (vs ~50 for libm tanhf)
__device__ inline float sigf(float x) {
    return __fdividef(1.f, 1.f + __expf(-x));
}
__device__ inline float tanhfast(float x) {
    return 1.f - __fdividef(2.f, 1.f + __expf(2.f * x));
}

__device__ inline void gll16(const void* g, void* l) {
    __builtin_amdgcn_global_load_lds(
        (const __attribute__((address_space(1))) unsigned int*)(uintptr_t)g,
        (__attribute__((address_space(3))) unsigned int*)(unsigned int)(uintptr_t)l,
        16, 0, 0);
}

// ---- shared GEMM core: stage 128x32 A/B tiles, 4 waves 2x2, 16x16x32 ----
#define GEMM_CORE(A_, Bt_, K_)                                                 \
    for (int k0 = 0; k0 < (K_); k0 += 32) {                                    \
        _Pragma("unroll")                                                      \
        for (int j = 0; j < 2; ++j) {                                          \
            const int idx = j * 256 + tid;                                     \
            const int row = idx >> 2, kc = idx & 3;                            \
            gll16((A_)  + (size_t)(m0 + row) * (K_) + k0 + kc * 8, As + idx*8);\
            gll16((Bt_) + (size_t)(n0 + row) * (K_) + k0 + kc * 8, Bs + idx*8);\
        }                                                                      \
        __syncthreads();                                                       \
        bf16x8 aF[4], bF[4];                                                   \
        _Pragma("unroll")                                                      \
        for (int mi = 0; mi < 4; ++mi)                                         \
            aF[mi] = *(const bf16x8*)(As + (wr*64 + mi*16 + lm)*32 + quad*8);  \
        _Pragma("unroll")                                                      \
        for (int ni = 0; ni < 4; ++ni)                                         \
            bF[ni] = *(const bf16x8*)(Bs + (wc*64 + ni*16 + lm)*32 + quad*8);  \
        _Pragma("unroll")                                                      \
        for (int mi = 0; mi < 4; ++mi)                                         \
            _Pragma("unroll")                                                  \
            for (int ni = 0; ni < 4; ++ni)                                     \
                acc[mi][ni] = __builtin_amdgcn_mfma_f32_16x16x32_bf16(         \
                    aF[mi], bF[ni], acc[mi][ni], 0, 0, 0);                     \
        __syncthreads();                                                       \
    }

// ---- plain GEMM (MLP): C = act(A @ Bt^T + bias) ----
template <int EPI, int OUT_BF16, int NGUARD>
__global__ __launch_bounds__(256)
void gemm_mfma(const unsigned short* __restrict__ A,
               const unsigned short* __restrict__ Bt,
               const float* __restrict__ bias,
               void* __restrict__ Cv, int ldc, int Nreal, int K)
{
    __shared__ __attribute__((aligned(16))) unsigned short As[128 * 32];
    __shared__ __attribute__((aligned(16))) unsigned short Bs[128 * 32];
    const int tid  = threadIdx.x;
    const int lane = tid & 63;
    const int w    = tid >> 6;
    const int wr   = w >> 1, wc = w & 1;
    const int lm   = lane & 15, quad = lane >> 4;
    const int m0   = blockIdx.x * 128, n0 = blockIdx.y * 128;
    f32x4 acc[4][4] = {};
    GEMM_CORE(A, Bt, K)
    #pragma unroll
    for (int mi = 0; mi < 4; ++mi)
        #pragma unroll
        for (int r = 0; r < 4; ++r) {
            const size_t row = m0 + wr * 64 + mi * 16 + quad * 4 + r;
            #pragma unroll
            for (int ni = 0; ni < 4; ++ni) {
                const int col = n0 + wc * 64 + ni * 16 + lm;
                if (!NGUARD || col < Nreal) {
                    float v = acc[mi][ni][r] + bias[col];
                    if (EPI == EPI_RELU) v = fmaxf(v, 0.f);
                    if (EPI == EPI_TANH) v = tanhfast(v);
                    if (OUT_BF16) ((unsigned short*)Cv)[row * ldc + col] = f2bf(v);
                    else          ((float*)Cv)[row * ldc + col] = v;
                }
            }
        }
}

// ---- LSTM GEMM: z = A @ Wt^T + biasI, gates fused in epilogue. ----
// Wt cols interleaved: n' = (u>>4)*64 + g*16 + (u&15); lane's 4 ni accs =
// (i,f,g,o) of unit u = ((n0+wc*64)>>6)*16 + lm.
__global__ __launch_bounds__(256)
void gemm_lstm(const unsigned short* __restrict__ A,
               const unsigned short* __restrict__ Bt,
               const float* __restrict__ biasI,
               float* __restrict__ c,
               unsigned short* __restrict__ hdst, int ldh, int hoff,
               unsigned short* __restrict__ dec, int doff, int K)
{
    __shared__ __attribute__((aligned(16))) unsigned short As[128 * 32];
    __shared__ __attribute__((aligned(16))) unsigned short Bs[128 * 32];
    const int tid  = threadIdx.x;
    const int lane = tid & 63;
    const int w    = tid >> 6;
    const int wr   = w >> 1, wc = w & 1;
    const int lm   = lane & 15, quad = lane >> 4;
    const int m0   = blockIdx.x * 128, n0 = blockIdx.y * 128;
    f32x4 acc[4][4] = {};
    GEMM_CORE(A, Bt, K)
    const int u = ((n0 + wc * 64) >> 6) * 16 + lm;
    if (u >= 356) return;
    float bI[4];
    #pragma unroll
    for (int ni = 0; ni < 4; ++ni) bI[ni] = biasI[n0 + wc * 64 + ni * 16 + lm];
    #pragma unroll
    for (int mi = 0; mi < 4; ++mi)
        #pragma unroll
        for (int r = 0; r < 4; ++r) {
            const size_t row = m0 + wr * 64 + mi * 16 + quad * 4 + r;
            const float zi = acc[mi][0][r] + bI[0];
            const float zf = acc[mi][1][r] + bI[1];
            const float zg = acc[mi][2][r] + bI[2];
            const float zo = acc[mi][3][r] + bI[3];
            const size_t ci = row * 356 + u;
            const float cn = sigf(zf) * c[ci] + sigf(zi) * tanhfast(zg);
            c[ci] = cn;
            const unsigned short hb = f2bf(sigf(zo) * tanhfast(cn));
            if (hdst) hdst[row * (size_t)ldh + hoff + u] = hb;
            if (dec)  dec[row * (size_t)2496 + doff + u] = hb;
        }
}

// ---- LSTM weight pack: [Wa;Wb] fp32 [K][1424] -> Wt bf16 [1536][Kp] ----
__global__ void pack_lstm(const float* __restrict__ Wa,
                          const float* __restrict__ Wb, int K1, int K,
                          const float* __restrict__ bias,
                          unsigned short* __restrict__ Wt,
                          float* __restrict__ biasI, int Kp)
{
    const int idx = blockIdx.x * 256 + threadIdx.x;
    if (idx >= 1536 * Kp) return;
    const int np = idx / Kp, k = idx - np * Kp;
    const int ub = np >> 6, g = (np >> 4) & 3, ul = np & 15;
    const int u = ub * 16 + ul;
    const bool valid = (u < 356);
    const int norig = g * 356 + u;
    float v = 0.f;
    if (valid && k < K)
        v = (k < K1) ? Wa[(size_t)k * 1424 + norig]
                     : Wb[(size_t)(k - K1) * 1424 + norig];
    Wt[(size_t)np * Kp + k] = f2bf(v);
    if (k == 0) biasI[np] = valid ? bias[norig] : 0.f;
}

// ---- MLP weight transpose+pack (fp32 [K][N] -> bf16 [Np][Kp]) ----
__global__ void transpose_pack(const float* __restrict__ W, int K, int N,
                               unsigned short* __restrict__ Wt, int Kp, int Np)
{
    __shared__ float t[32][33];
    const int n0 = blockIdx.x * 32, k0 = blockIdx.y * 32;
    const int tx = threadIdx.x, ty = threadIdx.y;
    #pragma unroll
    for (int r = 0; r < 4; ++r) {
        const int k = k0 + ty + 8 * r, n = n0 + tx;
        t[ty + 8 * r][tx] = (k < K && n < N) ? W[(size_t)k * N + n] : 0.f;
    }
    __syncthreads();
    #pragma unroll
    for (int r = 0; r < 4; ++r) {
        const int k = k0 + tx, n = n0 + ty + 8 * r;
        if (k < Kp && n < Np) Wt[(size_t)n * Kp + k] = f2bf(t[tx][ty + 8 * r]);
    }
}

// three 1024x1024 transposes in one launch (blockIdx.z selects)
struct WP3 { const float *s0, *s1, *s2; unsigned short *d0, *d1, *d2; };
__global__ void transpose_pack3(WP3 p)
{
    __shared__ float t[32][33];
    const float* W = (blockIdx.z == 0) ? p.s0 : (blockIdx.z == 1) ? p.s1 : p.s2;
    unsigned short* Wt = (blockIdx.z == 0) ? p.d0 : (blockIdx.z == 1) ? p.d1 : p.d2;
    const int n0 = blockIdx.x * 32, k0 = blockIdx.y * 32;
    const int tx = threadIdx.x, ty = threadIdx.y;
    #pragma unroll
    for (int r = 0; r < 4; ++r)
        t[ty + 8 * r][tx] = W[(size_t)(k0 + ty + 8 * r) * 1024 + n0 + tx];
    __syncthreads();
    #pragma unroll
    for (int r = 0; r < 4; ++r)
        Wt[(size_t)(n0 + ty + 8 * r) * 1024 + k0 + tx] = f2bf(t[tx][ty + 8 * r]);
}

// ---- targeted pad zeroing (replaces 140 MB of memsets with 16 MB) ----
// r0: AcE t=0 cols[69,448)   r1: AcE t=1..6 cols[425,448)
// r2: AcD t=0 cols[45,416)   r3: AcD t=1..6 cols[401,416)
// r4: dcd cols[2492,2496)    r5: c (fp32, as 2 shorts/elem)
__global__ void zero_pads(unsigned short* __restrict__ AcE,
                          unsigned short* __restrict__ AcD,
                          unsigned short* __restrict__ dcd,
                          unsigned short* __restrict__ cc)
{
    const size_t N0 = (size_t)8192 * 379, N1 = (size_t)6 * 8192 * 23;
    const size_t N2 = (size_t)8192 * 371, N3 = (size_t)6 * 8192 * 15;
    const size_t N4 = (size_t)8192 * 4,   N5 = (size_t)8192 * 356 * 2;
    size_t i = (size_t)blockIdx.x * 256 + threadIdx.x;
    if (i < N0) { const size_t r = i / 379; AcE[r * 448 + 69 + i % 379] = 0; return; }
    i -= N0;
    if (i < N1) { const size_t r = 8192 + i / 23; AcE[r * 448 + 425 + i % 23] = 0; return; }
    i -= N1;
    if (i < N2) { const size_t r = i / 371; AcD[r * 416 + 45 + i % 371] = 0; return; }
    i -= N2;
    if (i < N3) { const size_t r = 8192 + i / 15; AcD[r * 416 + 401 + i % 15] = 0; return; }
    i -= N3;
    if (i < N4) { dcd[(i / 4) * 2496 + 2492 + (i & 3)] = 0; return; }
    i -= N4;
    if (i < N5) cc[i] = 0;
}

// ---- fill x/m time-slices into the 7 per-step concat buffers (bf16) ----
__global__ void fill_slices(const float* __restrict__ src,
                            unsigned short* __restrict__ bufs,
                            int F, int Kp, int n)
{
    const int i = blockIdx.x * 256 + threadIdx.x;
    if (i >= n) return;
    const int b = i / (7 * F), rem = i - b * 7 * F;
    const int t = rem / F, f = rem - t * F;
    bufs[(size_t)t * 8192 * Kp + (size_t)b * Kp + f] = f2bf(src[i]);
}

extern "C" void kernel_launch(void* const* d_in, const int* in_sizes, int n_in,
                              void* d_out, int out_size, void* d_ws, size_t ws_size,
                              hipStream_t stream)
{
    const float* x     = (const float*)d_in[0];
    const float* m     = (const float*)d_in[1];
    const float* enc_W = (const float*)d_in[2];
    const float* enc_U = (const float*)d_in[3];
    const float* enc_b = (const float*)d_in[4];
    const float* dec_W = (const float*)d_in[5];
    const float* dec_Um= (const float*)d_in[6];
    const float* dec_b = (const float*)d_in[7];
    const float* W_map = (const float*)d_in[8];
    const float* b_map = (const float*)d_in[9];
    const float* W1    = (const float*)d_in[10];
    const float* b1    = (const float*)d_in[11];
    const float* W2    = (const float*)d_in[12];
    const float* b2    = (const float*)d_in[13];
    const float* W3    = (const float*)d_in[14];
    const float* b3    = (const float*)d_in[15];
    const float* W_out = (const float*)d_in[16];
    const float* b_out = (const float*)d_in[17];
    float* out = (float*)d_out;

    const int B = 8192, T = 7, FE = 69, FD = 45;
    const int KE = 448, KD = 416, KMP = 2496;

    char* ws = (char*)d_ws;
    size_t off = 0;
    auto alloc = [&](size_t bytes) -> void* {
        void* p = ws + off; off = (off + bytes + 255) & ~(size_t)255; return p;
    };
    unsigned short* WtE = (unsigned short*)alloc((size_t)1536 * KE * 2);
    unsigned short* WtD = (unsigned short*)alloc((size_t)1536 * KD * 2);
    unsigned short* WtM = (unsigned short*)alloc((size_t)1024 * KMP * 2);
    unsigned short* Wt1 = (unsigned short*)alloc((size_t)1024 * 1024 * 2);
    unsigned short* Wt2 = (unsigned short*)alloc((size_t)1024 * 1024 * 2);
    unsigned short* Wt3 = (unsigned short*)alloc((size_t)1024 * 1024 * 2);
    unsigned short* WtO = (unsigned short*)alloc((size_t)256 * 1024 * 2);
    float* bIE = (float*)alloc(1536 * 4);
    float* bID = (float*)alloc(1536 * 4);
    unsigned short* AcE = (unsigned short*)alloc((size_t)T * B * KE * 2);
    unsigned short* AcD = (unsigned short*)alloc((size_t)T * B * KD * 2);
    unsigned short* dcd = (unsigned short*)alloc((size_t)B * KMP * 2);
    unsigned short* a1  = (unsigned short*)alloc((size_t)B * 1024 * 2);
    unsigned short* a2  = (unsigned short*)alloc((size_t)B * 1024 * 2);
    float* c = (float*)alloc((size_t)B * 356 * 4);

    // ---- weight packing ----
    pack_lstm<<<(1536 * KE + 255) / 256, 256, 0, stream>>>(
        enc_W, enc_U, FE, FE + 356, enc_b, WtE, bIE, KE);
    pack_lstm<<<(1536 * KD + 255) / 256, 256, 0, stream>>>(
        dec_W, dec_Um, FD, FD + 356, dec_b, WtD, bID, KD);
    const dim3 tb(32, 8);
    transpose_pack<<<dim3(1024 / 32, KMP / 32), tb, 0, stream>>>(
        W_map, 2492, 1024, WtM, KMP, 1024);
    WP3 p3{W1, W2, W3, Wt1, Wt2, Wt3};
    transpose_pack3<<<dim3(32, 32, 3), tb, 0, stream>>>(p3);
    transpose_pack<<<dim3(256 / 32, 1024 / 32), tb, 0, stream>>>(
        W_out, 1024, 168, WtO, 1024, 256);

    // ---- targeted zero: pads + t0 h-regions + c (one small launch) ----
    {
        const size_t tot = (size_t)8192 * 379 + (size_t)6 * 8192 * 23
                         + (size_t)8192 * 371 + (size_t)6 * 8192 * 15
                         + (size_t)8192 * 4   + (size_t)8192 * 356 * 2;
        zero_pads<<<(unsigned)((tot + 255) / 256), 256, 0, stream>>>(
            AcE, AcD, dcd, (unsigned short*)c);
    }

    fill_slices<<<(B * T * FE + 255) / 256, 256, 0, stream>>>(x, AcE, FE, KE, B * T * FE);
    fill_slices<<<(B * T * FD + 255) / 256, 256, 0, stream>>>(m, AcD, FD, KD, B * T * FD);

    // ---- sequential LSTM chain: 14 fused GEMM launches ----
    const dim3 gz(64, 12);
    for (int t = 0; t < T; ++t) {
        unsigned short* At = AcE + (size_t)t * B * KE;
        unsigned short* hdst = (t < 6) ? AcE + (size_t)(t + 1) * B * KE : AcD;
        gemm_lstm<<<gz, 256, 0, stream>>>(
            At, WtE, bIE, c, hdst, (t < 6) ? KE : KD, (t < 6) ? FE : FD,
            nullptr, 0, KE);
    }
    for (int t = 0; t < T; ++t) {
        unsigned short* At = AcD + (size_t)t * B * KD;
        unsigned short* hdst = (t < 6) ? AcD + (size_t)(t + 1) * B * KD : nullptr;
        gemm_lstm<<<gz, 256, 0, stream>>>(
            At, WtD, bID, c, hdst, KD, FD, dcd, t * 356, KD);
    }

    // ---- MLP head ----
    gemm_mfma<EPI_RELU, 1, 0><<<dim3(64, 8), 256, 0, stream>>>(
        dcd, WtM, b_map, a1, 1024, 1024, KMP);
    gemm_mfma<EPI_TANH, 1, 0><<<dim3(64, 8), 256, 0, stream>>>(
        a1, Wt1, b1, a2, 1024, 1024, 1024);
    gemm_mfma<EPI_TANH, 1, 0><<<dim3(64, 8), 256, 0, stream>>>(
        a2, Wt2, b2, a1, 1024, 1024, 1024);
    gemm_mfma<EPI_TANH, 1, 0><<<dim3(64, 8), 256, 0, stream>>>(
        a1, Wt3, b3, a2, 1024, 1024, 1024);
    gemm_mfma<EPI_NONE, 0, 1><<<dim3(64, 2), 256, 0, stream>>>(
        a2, WtO, b_out, out, 168, 168, 1024);
}

// Round 7
// 633.001 us; speedup vs baseline: 2.7200x; 1.1285x over previous
//
#include <hip/hip_runtime.h>
#include <math.h>

// ---------------------------------------------------------------------------
// Round 7: r6 structure + double-buffered single-barrier GEMM K-loop.
// Old: stage -> sync(drain BEFORE compute) -> mfma -> sync  (2 barriers/iter)
// New: [stage i+1 async] -> mfma(i) -> sync  (1 barrier/iter; the vmcnt drain
// at the barrier overlaps the whole MFMA phase). Buffers alternate: stage
// writes buf[(i+1)&1], compute reads buf[i&1] -> RAW/WAR safe with 1 barrier.
// LDS 32 KB (4 x 8 KB). Everything else as round 6 (best: 714 us).
// ---------------------------------------------------------------------------

using bf16x8 = __attribute__((ext_vector_type(8))) short;
using f32x4  = __attribute__((ext_vector_type(4))) float;

enum { EPI_NONE = 0, EPI_RELU = 1, EPI_TANH = 2 };

__device__ inline unsigned short f2bf(float f) {
    union { float f; unsigned u; } v; v.f = f;
    unsigned r = v.u + 0x7FFFu + ((v.u >> 16) & 1u);
    return (unsigned short)(r >> 16);
}
// fast sigmoid/tanh: v_exp_f32-based (~5 instr vs ~50 libm)
__device__ inline float sigf(float x) {
    return __fdividef(1.f, 1.f + __expf(-x));
}
__device__ inline float tanhfast(float x) {
    return 1.f - __fdividef(2.f, 1.f + __expf(2.f * x));
}

__device__ inline void gll16(const void* g, void* l) {
    __builtin_amdgcn_global_load_lds(
        (const __attribute__((address_space(1))) unsigned int*)(uintptr_t)g,
        (__attribute__((address_space(3))) unsigned int*)(unsigned int)(uintptr_t)l,
        16, 0, 0);
}

// stage one 128x32 A-tile + B-tile into buffer b_ (async, no wait)
#define STAGE(A_, Bt_, K_, k0_, b_)                                            \
    _Pragma("unroll")                                                          \
    for (int j = 0; j < 2; ++j) {                                              \
        const int idx = j * 256 + tid;                                         \
        const int row = idx >> 2, kc = idx & 3;                                \
        gll16((A_)  + (size_t)(m0 + row) * (K_) + (k0_) + kc * 8,              \
              (void*)&As[b_][idx * 8]);                                        \
        gll16((Bt_) + (size_t)(n0 + row) * (K_) + (k0_) + kc * 8,              \
              (void*)&Bs[b_][idx * 8]);                                        \
    }

// double-buffered K-loop: one barrier per iter, drain overlapped with MFMA
#define GEMM_CORE(A_, Bt_, K_)                                                 \
    STAGE(A_, Bt_, K_, 0, 0)                                                   \
    {                                                                          \
        const int niter = (K_) / 32;                                           \
        for (int it = 0; it < niter; ++it) {                                   \
            __syncthreads();            /* drains stage(it); all waves sync */ \
            if (it + 1 < niter) {                                              \
                const int kn = (it + 1) * 32, bn = (it + 1) & 1;               \
                STAGE(A_, Bt_, K_, kn, bn)                                     \
            }                                                                  \
            const unsigned short* Asb = As[it & 1];                            \
            const unsigned short* Bsb = Bs[it & 1];                            \
            bf16x8 aF[4], bF[4];                                               \
            _Pragma("unroll")                                                  \
            for (int mi = 0; mi < 4; ++mi)                                     \
                aF[mi] = *(const bf16x8*)(Asb + (wr*64 + mi*16 + lm)*32 + quad*8);\
            _Pragma("unroll")                                                  \
            for (int ni = 0; ni < 4; ++ni)                                     \
                bF[ni] = *(const bf16x8*)(Bsb + (wc*64 + ni*16 + lm)*32 + quad*8);\
            _Pragma("unroll")                                                  \
            for (int mi = 0; mi < 4; ++mi)                                     \
                _Pragma("unroll")                                              \
                for (int ni = 0; ni < 4; ++ni)                                 \
                    acc[mi][ni] = __builtin_amdgcn_mfma_f32_16x16x32_bf16(     \
                        aF[mi], bF[ni], acc[mi][ni], 0, 0, 0);                 \
        }                                                                      \
    }

#define GEMM_PREAMBLE                                                          \
    __shared__ __attribute__((aligned(16))) unsigned short As[2][128 * 32];    \
    __shared__ __attribute__((aligned(16))) unsigned short Bs[2][128 * 32];    \
    const int tid  = threadIdx.x;                                              \
    const int lane = tid & 63;                                                 \
    const int w    = tid >> 6;                                                 \
    const int wr   = w >> 1, wc = w & 1;                                       \
    const int lm   = lane & 15, quad = lane >> 4;                              \
    const int m0   = blockIdx.x * 128, n0 = blockIdx.y * 128;                  \
    f32x4 acc[4][4] = {};

// ---- plain GEMM (MLP): C = act(A @ Bt^T + bias) ----
template <int EPI, int OUT_BF16, int NGUARD>
__global__ __launch_bounds__(256)
void gemm_mfma(const unsigned short* __restrict__ A,
               const unsigned short* __restrict__ Bt,
               const float* __restrict__ bias,
               void* __restrict__ Cv, int ldc, int Nreal, int K)
{
    GEMM_PREAMBLE
    GEMM_CORE(A, Bt, K)
    #pragma unroll
    for (int mi = 0; mi < 4; ++mi)
        #pragma unroll
        for (int r = 0; r < 4; ++r) {
            const size_t row = m0 + wr * 64 + mi * 16 + quad * 4 + r;
            #pragma unroll
            for (int ni = 0; ni < 4; ++ni) {
                const int col = n0 + wc * 64 + ni * 16 + lm;
                if (!NGUARD || col < Nreal) {
                    float v = acc[mi][ni][r] + bias[col];
                    if (EPI == EPI_RELU) v = fmaxf(v, 0.f);
                    if (EPI == EPI_TANH) v = tanhfast(v);
                    if (OUT_BF16) ((unsigned short*)Cv)[row * ldc + col] = f2bf(v);
                    else          ((float*)Cv)[row * ldc + col] = v;
                }
            }
        }
}

// ---- LSTM GEMM: z = A @ Wt^T + biasI, gates fused in epilogue ----
// Wt cols interleaved: n' = (u>>4)*64 + g*16 + (u&15); lane's 4 ni accs =
// (i,f,g,o) of unit u = ((n0+wc*64)>>6)*16 + lm.
__global__ __launch_bounds__(256)
void gemm_lstm(const unsigned short* __restrict__ A,
               const unsigned short* __restrict__ Bt,
               const float* __restrict__ biasI,
               float* __restrict__ c,
               unsigned short* __restrict__ hdst, int ldh, int hoff,
               unsigned short* __restrict__ dec, int doff, int K)
{
    GEMM_PREAMBLE
    GEMM_CORE(A, Bt, K)
    const int u = ((n0 + wc * 64) >> 6) * 16 + lm;
    if (u >= 356) return;
    float bI[4];
    #pragma unroll
    for (int ni = 0; ni < 4; ++ni) bI[ni] = biasI[n0 + wc * 64 + ni * 16 + lm];
    #pragma unroll
    for (int mi = 0; mi < 4; ++mi)
        #pragma unroll
        for (int r = 0; r < 4; ++r) {
            const size_t row = m0 + wr * 64 + mi * 16 + quad * 4 + r;
            const float zi = acc[mi][0][r] + bI[0];
            const float zf = acc[mi][1][r] + bI[1];
            const float zg = acc[mi][2][r] + bI[2];
            const float zo = acc[mi][3][r] + bI[3];
            const size_t ci = row * 356 + u;
            const float cn = sigf(zf) * c[ci] + sigf(zi) * tanhfast(zg);
            c[ci] = cn;
            const unsigned short hb = f2bf(sigf(zo) * tanhfast(cn));
            if (hdst) hdst[row * (size_t)ldh + hoff + u] = hb;
            if (dec)  dec[row * (size_t)2496 + doff + u] = hb;
        }
}

// ---- LSTM weight pack (enc+dec in one launch; blockIdx.y selects) ----
// [Wa;Wb] fp32 [K][1424] -> Wt bf16 [1536][Kp], gate-interleaved, zero-pad.
struct PackArgs {
    const float *Wa0, *Wb0, *bias0; unsigned short* Wt0; float* bI0; int K10, K0, Kp0;
    const float *Wa1, *Wb1, *bias1; unsigned short* Wt1; float* bI1; int K11, K1, Kp1;
};
__global__ void pack_lstm2(PackArgs p)
{
    const float* Wa  = blockIdx.y ? p.Wa1  : p.Wa0;
    const float* Wb  = blockIdx.y ? p.Wb1  : p.Wb0;
    const float* bias= blockIdx.y ? p.bias1: p.bias0;
    unsigned short* Wt = blockIdx.y ? p.Wt1 : p.Wt0;
    float* biasI = blockIdx.y ? p.bI1 : p.bI0;
    const int K1 = blockIdx.y ? p.K11 : p.K10;
    const int K  = blockIdx.y ? p.K1  : p.K0;
    const int Kp = blockIdx.y ? p.Kp1 : p.Kp0;
    const int idx = blockIdx.x * 256 + threadIdx.x;
    if (idx >= 1536 * Kp) return;
    const int np = idx / Kp, k = idx - np * Kp;
    const int ub = np >> 6, g = (np >> 4) & 3, ul = np & 15;
    const int u = ub * 16 + ul;
    const bool valid = (u < 356);
    const int norig = g * 356 + u;
    float v = 0.f;
    if (valid && k < K)
        v = (k < K1) ? Wa[(size_t)k * 1424 + norig]
                     : Wb[(size_t)(k - K1) * 1424 + norig];
    Wt[(size_t)np * Kp + k] = f2bf(v);
    if (k == 0) biasI[np] = valid ? bias[norig] : 0.f;
}

// ---- MLP weight transpose+pack (fp32 [K][N] -> bf16 [Np][Kp]) ----
__global__ void transpose_pack(const float* __restrict__ W, int K, int N,
                               unsigned short* __restrict__ Wt, int Kp, int Np)
{
    __shared__ float t[32][33];
    const int n0 = blockIdx.x * 32, k0 = blockIdx.y * 32;
    const int tx = threadIdx.x, ty = threadIdx.y;
    #pragma unroll
    for (int r = 0; r < 4; ++r) {
        const int k = k0 + ty + 8 * r, n = n0 + tx;
        t[ty + 8 * r][tx] = (k < K && n < N) ? W[(size_t)k * N + n] : 0.f;
    }
    __syncthreads();
    #pragma unroll
    for (int r = 0; r < 4; ++r) {
        const int k = k0 + tx, n = n0 + ty + 8 * r;
        if (k < Kp && n < Np) Wt[(size_t)n * Kp + k] = f2bf(t[tx][ty + 8 * r]);
    }
}

// three 1024x1024 transposes in one launch (blockIdx.z selects)
struct WP3 { const float *s0, *s1, *s2; unsigned short *d0, *d1, *d2; };
__global__ void transpose_pack3(WP3 p)
{
    __shared__ float t[32][33];
    const float* W = (blockIdx.z == 0) ? p.s0 : (blockIdx.z == 1) ? p.s1 : p.s2;
    unsigned short* Wt = (blockIdx.z == 0) ? p.d0 : (blockIdx.z == 1) ? p.d1 : p.d2;
    const int n0 = blockIdx.x * 32, k0 = blockIdx.y * 32;
    const int tx = threadIdx.x, ty = threadIdx.y;
    #pragma unroll
    for (int r = 0; r < 4; ++r)
        t[ty + 8 * r][tx] = W[(size_t)(k0 + ty + 8 * r) * 1024 + n0 + tx];
    __syncthreads();
    #pragma unroll
    for (int r = 0; r < 4; ++r)
        Wt[(size_t)(n0 + ty + 8 * r) * 1024 + k0 + tx] = f2bf(t[tx][ty + 8 * r]);
}

// ---- targeted pad zeroing (16 MB instead of 140 MB of memsets) ----
__global__ void zero_pads(unsigned short* __restrict__ AcE,
                          unsigned short* __restrict__ AcD,
                          unsigned short* __restrict__ dcd,
                          unsigned short* __restrict__ cc)
{
    const size_t N0 = (size_t)8192 * 379, N1 = (size_t)6 * 8192 * 23;
    const size_t N2 = (size_t)8192 * 371, N3 = (size_t)6 * 8192 * 15;
    const size_t N4 = (size_t)8192 * 4,   N5 = (size_t)8192 * 356 * 2;
    size_t i = (size_t)blockIdx.x * 256 + threadIdx.x;
    if (i < N0) { const size_t r = i / 379; AcE[r * 448 + 69 + i % 379] = 0; return; }
    i -= N0;
    if (i < N1) { const size_t r = 8192 + i / 23; AcE[r * 448 + 425 + i % 23] = 0; return; }
    i -= N1;
    if (i < N2) { const size_t r = i / 371; AcD[r * 416 + 45 + i % 371] = 0; return; }
    i -= N2;
    if (i < N3) { const size_t r = 8192 + i / 15; AcD[r * 416 + 401 + i % 15] = 0; return; }
    i -= N3;
    if (i < N4) { dcd[(i / 4) * 2496 + 2492 + (i & 3)] = 0; return; }
    i -= N4;
    if (i < N5) cc[i] = 0;
}

// ---- fill x AND m time-slices into the per-step concat buffers (bf16) ----
__global__ void fill_slices2(const float* __restrict__ x,
                             const float* __restrict__ m,
                             unsigned short* __restrict__ AcE,
                             unsigned short* __restrict__ AcD)
{
    const int NX = 8192 * 7 * 69;
    int i = blockIdx.x * 256 + threadIdx.x;
    if (i < NX) {
        const int b = i / (7 * 69), rem = i - b * 7 * 69;
        const int t = rem / 69, f = rem - t * 69;
        AcE[(size_t)t * 8192 * 448 + (size_t)b * 448 + f] = f2bf(x[i]);
        return;
    }
    i -= NX;
    if (i < 8192 * 7 * 45) {
        const int b = i / (7 * 45), rem = i - b * 7 * 45;
        const int t = rem / 45, f = rem - t * 45;
        AcD[(size_t)t * 8192 * 416 + (size_t)b * 416 + f] = f2bf(m[i]);
    }
}

extern "C" void kernel_launch(void* const* d_in, const int* in_sizes, int n_in,
                              void* d_out, int out_size, void* d_ws, size_t ws_size,
                              hipStream_t stream)
{
    const float* x     = (const float*)d_in[0];
    const float* m     = (const float*)d_in[1];
    const float* enc_W = (const float*)d_in[2];
    const float* enc_U = (const float*)d_in[3];
    const float* enc_b = (const float*)d_in[4];
    const float* dec_W = (const float*)d_in[5];
    const float* dec_Um= (const float*)d_in[6];
    const float* dec_b = (const float*)d_in[7];
    const float* W_map = (const float*)d_in[8];
    const float* b_map = (const float*)d_in[9];
    const float* W1    = (const float*)d_in[10];
    const float* b1    = (const float*)d_in[11];
    const float* W2    = (const float*)d_in[12];
    const float* b2    = (const float*)d_in[13];
    const float* W3    = (const float*)d_in[14];
    const float* b3    = (const float*)d_in[15];
    const float* W_out = (const float*)d_in[16];
    const float* b_out = (const float*)d_in[17];
    float* out = (float*)d_out;

    const int B = 8192, T = 7, FE = 69, FD = 45;
    const int KE = 448, KD = 416, KMP = 2496;

    char* ws = (char*)d_ws;
    size_t off = 0;
    auto alloc = [&](size_t bytes) -> void* {
        void* p = ws + off; off = (off + bytes + 255) & ~(size_t)255; return p;
    };
    unsigned short* WtE = (unsigned short*)alloc((size_t)1536 * KE * 2);
    unsigned short* WtD = (unsigned short*)alloc((size_t)1536 * KD * 2);
    unsigned short* WtM = (unsigned short*)alloc((size_t)1024 * KMP * 2);
    unsigned short* Wt1 = (unsigned short*)alloc((size_t)1024 * 1024 * 2);
    unsigned short* Wt2 = (unsigned short*)alloc((size_t)1024 * 1024 * 2);
    unsigned short* Wt3 = (unsigned short*)alloc((size_t)1024 * 1024 * 2);
    unsigned short* WtO = (unsigned short*)alloc((size_t)256 * 1024 * 2);
    float* bIE = (float*)alloc(1536 * 4);
    float* bID = (float*)alloc(1536 * 4);
    unsigned short* AcE = (unsigned short*)alloc((size_t)T * B * KE * 2);
    unsigned short* AcD = (unsigned short*)alloc((size_t)T * B * KD * 2);
    unsigned short* dcd = (unsigned short*)alloc((size_t)B * KMP * 2);
    unsigned short* a1  = (unsigned short*)alloc((size_t)B * 1024 * 2);
    unsigned short* a2  = (unsigned short*)alloc((size_t)B * 1024 * 2);
    float* c = (float*)alloc((size_t)B * 356 * 4);

    // ---- weight packing ----
    PackArgs pa{enc_W, enc_U, enc_b, WtE, bIE, FE, FE + 356, KE,
                dec_W, dec_Um, dec_b, WtD, bID, FD, FD + 356, KD};
    pack_lstm2<<<dim3((1536 * KE + 255) / 256, 2), 256, 0, stream>>>(pa);
    const dim3 tb(32, 8);
    transpose_pack<<<dim3(1024 / 32, KMP / 32), tb, 0, stream>>>(
        W_map, 2492, 1024, WtM, KMP, 1024);
    WP3 p3{W1, W2, W3, Wt1, Wt2, Wt3};
    transpose_pack3<<<dim3(32, 32, 3), tb, 0, stream>>>(p3);
    transpose_pack<<<dim3(256 / 32, 1024 / 32), tb, 0, stream>>>(
        W_out, 1024, 168, WtO, 1024, 256);

    // ---- targeted zero: pads + t0 h-regions + c ----
    {
        const size_t tot = (size_t)8192 * 379 + (size_t)6 * 8192 * 23
                         + (size_t)8192 * 371 + (size_t)6 * 8192 * 15
                         + (size_t)8192 * 4   + (size_t)8192 * 356 * 2;
        zero_pads<<<(unsigned)((tot + 255) / 256), 256, 0, stream>>>(
            AcE, AcD, dcd, (unsigned short*)c);
    }
    fill_slices2<<<(B * T * (FE + FD) + 255) / 256, 256, 0, stream>>>(
        x, m, AcE, AcD);

    // ---- sequential LSTM chain: 14 fused GEMM launches ----
    const dim3 gz(64, 12);
    for (int t = 0; t < T; ++t) {
        unsigned short* At = AcE + (size_t)t * B * KE;
        unsigned short* hdst = (t < 6) ? AcE + (size_t)(t + 1) * B * KE : AcD;
        gemm_lstm<<<gz, 256, 0, stream>>>(
            At, WtE, bIE, c, hdst, (t < 6) ? KE : KD, (t < 6) ? FE : FD,
            nullptr, 0, KE);
    }
    for (int t = 0; t < T; ++t) {
        unsigned short* At = AcD + (size_t)t * B * KD;
        unsigned short* hdst = (t < 6) ? AcD + (size_t)(t + 1) * B * KD : nullptr;
        gemm_lstm<<<gz, 256, 0, stream>>>(
            At, WtD, bID, c, hdst, KD, FD, dcd, t * 356, KD);
    }

    // ---- MLP head ----
    gemm_mfma<EPI_RELU, 1, 0><<<dim3(64, 8), 256, 0, stream>>>(
        dcd, WtM, b_map, a1, 1024, 1024, KMP);
    gemm_mfma<EPI_TANH, 1, 0><<<dim3(64, 8), 256, 0, stream>>>(
        a1, Wt1, b1, a2, 1024, 1024, 1024);
    gemm_mfma<EPI_TANH, 1, 0><<<dim3(64, 8), 256, 0, stream>>>(
        a2, Wt2, b2, a1, 1024, 1024, 1024);
    gemm_mfma<EPI_TANH, 1, 0><<<dim3(64, 8), 256, 0, stream>>>(
        a1, Wt3, b3, a2, 1024, 1024, 1024);
    gemm_mfma<EPI_NONE, 0, 1><<<dim3(64, 2), 256, 0, stream>>>(
        a2, WtO, b_out, out, 168, 168, 1024);
}